// Round 1
// baseline (2281.108 us; speedup 1.0000x reference)
//
#include <hip/hip_runtime.h>
#include <hip/hip_bf16.h>

#define B_ 128
#define T_ 512
#define DIM_ 256
#define E_ 512
#define H_ 512
#define NB_ 32        // blocks per batch-group (sync domain)
#define NG_ 8         // batch groups
#define WROW 1032     // padded LDS row stride (1024 + 8) in bf16 elems

typedef __attribute__((ext_vector_type(8))) short short8;
typedef __attribute__((ext_vector_type(4))) float floatx4;
typedef unsigned long long ull_t;

__device__ __forceinline__ float sigmoidf_(float x) {
  return 1.0f / (1.0f + __expf(-x));
}

__device__ __forceinline__ short f2bs(float f) {
  __hip_bfloat16 h = __float2bfloat16(f);
  return *reinterpret_cast<short*>(&h);
}

// ---------------------------------------------------------------------------
// Kernel 0: convert We (fp32) -> bf16 workspace copy.
// ---------------------------------------------------------------------------
__global__ __launch_bounds__(256) void cvt_we(const float* __restrict__ src,
                                              __hip_bfloat16* __restrict__ dst,
                                              int n) {
  int i = blockIdx.x * 256 + threadIdx.x;
  if (i < n) dst[i] = __float2bfloat16(src[i]);
}

// ---------------------------------------------------------------------------
// Kernel 1: xe[b*T+t][e] = sum_d x_t[b,t,d] * We[e,d] + be[e]   (bf16 out)
// ---------------------------------------------------------------------------
__global__ __launch_bounds__(256) void embed_gemm(
    const float* __restrict__ A,             // x_t  [65536][256] fp32
    const __hip_bfloat16* __restrict__ W,    // Web  [512][256] bf16
    const float* __restrict__ bias,          // be   [512] fp32
    __hip_bfloat16* __restrict__ C)          // xe   [65536][512] bf16
{
  const int tid = threadIdx.x;
  const int lane = tid & 63;
  const int w = tid >> 6;
  const int q = lane >> 4;
  const int l15 = lane & 15;
  const int m0 = blockIdx.x * 32 + (w >> 1) * 16;
  const int n0 = (w & 1) * 256;

  const float* a_base = A + (size_t)(m0 + l15) * DIM_ + q * 8;

  floatx4 acc[16];
#pragma unroll
  for (int j = 0; j < 16; ++j) acc[j] = (floatx4){0.f, 0.f, 0.f, 0.f};

  for (int ks = 0; ks < 8; ++ks) {
    const float* ap = a_base + ks * 32;
    short8 a;
#pragma unroll
    for (int j = 0; j < 8; ++j) a[j] = f2bs(ap[j]);
    short8 bf[16];
#pragma unroll
    for (int j = 0; j < 16; ++j) {
      const short* b_ptr =
          (const short*)W + (n0 + j * 16 + l15) * DIM_ + ks * 32 + q * 8;
      bf[j] = *(const short8*)b_ptr;
    }
#pragma unroll
    for (int j = 0; j < 16; ++j)
      acc[j] = __builtin_amdgcn_mfma_f32_16x16x32_bf16(a, bf[j], acc[j], 0, 0, 0);
  }

#pragma unroll
  for (int j = 0; j < 16; ++j) {
    const int col = n0 + j * 16 + l15;
    const float bv = bias[col];
#pragma unroll
    for (int r = 0; r < 4; ++r) {
      const int row = m0 + q * 4 + r;
      C[(size_t)row * E_ + col] = __float2bfloat16(acc[j][r] + bv);
    }
  }
}

// ---------------------------------------------------------------------------
// Kernel 2: persistent LSTM. 256 blocks (1/CU), 256 thr.
// block = (group g = blk&7, slice jb = blk>>3): batches [g*16,g*16+16),
// dims [jb*16, jb*16+16), all 4 gates. Weights [64 rows x 1024 K] in LDS.
// Wave w: K-range [w*256,(w+1)*256): waves 0,1 -> xe (W), 2,3 -> h (R).
//
// SYNC PROTOCOL (v2 — flag-based, 2 barriers/step):
//   seq[g*NB_+jb] = t+2  means "this block's h(t+1) slice is visible in L2".
//   Published by tid0 AFTER __syncthreads() (sync2): every wave's s_waitcnt
//   vmcnt(0) before the barrier guarantees all of the block's hbuf atomic
//   stores are ack'd at the coherence point before the flag is written.
//   Consumers (waves 2,3 only) poll all 32 flags of their group with ONE
//   coalesced 32-dword atomic load + __all ballot; no RMW serialization,
//   no s_sleep quantization, no broadcast syncthreads.
//   Waves 0,1 never poll: their next-step x-partials + out store + xe
//   prefetch run inside the slack while waves 2,3 poll/load h. Their pbuf
//   write (post-sync2) is ordered vs combine reads by sync2(t)/sync1(t+1).
//   Slot-overwrite safety: a block stores hbuf slot (t+1)&1 only after its
//   sync1(t), which follows its waves' poll(t) (seq>=t+1), which implies
//   every block finished its h(t-1) reads (those precede that block's
//   sync2(t-1) where seq=t+1 was published).
// ---------------------------------------------------------------------------
__global__ __launch_bounds__(256, 1) void lstm_persist(
    const float* __restrict__ h0,
    const float* __restrict__ c0,
    const float* __restrict__ Wi_, const float* __restrict__ bi_,
    const float* __restrict__ Wf_, const float* __restrict__ bf_,
    const float* __restrict__ Wg_, const float* __restrict__ bg_,
    const float* __restrict__ Wo_, const float* __restrict__ bo_,
    const float* __restrict__ Ri_, const float* __restrict__ Rf_,
    const float* __restrict__ Rg_, const float* __restrict__ Ro_,
    const __hip_bfloat16* __restrict__ xe,   // [B*T][E] bf16
    unsigned* __restrict__ hbuf32,           // [2][B][H/2] packed 2xbf16
    unsigned* __restrict__ seq,              // [NG_][NB_] step flags
    float* __restrict__ out)                 // hidden_seq | h_last | c_last
{
  extern __shared__ short wts[];             // 64 * WROW bf16 = 132096 B
  __shared__ float pbuf[4][4][16][17];       // [wave][gate][m][n] partials (+pad)
  __shared__ float cbuf[16][16];             // fp32 cell state slice
  __shared__ float bias_s[4][16];

  const int tid = threadIdx.x;
  const int lane = tid & 63;
  const int w = tid >> 6;
  const int q = lane >> 4;
  const int l15 = lane & 15;
  const int blk = blockIdx.x;
  const int g = blk & 7;        // batch group
  const int jb = blk >> 3;      // dim slice
  const int b0 = g * 16;
  const int d0 = jb * 16;
  unsigned* seq_g = seq + g * NB_;
  ull_t* hbuf64 = (ull_t*)hbuf32;

  const float* Wp[4] = {Wi_, Wf_, Wg_, Wo_};
  const float* Rp[4] = {Ri_, Rf_, Rg_, Ro_};
  const float* bp[4] = {bi_, bf_, bg_, bo_};

  // ---- load weights into LDS: row (G*16+dl) = [W_G[d0+dl][0:512] | R_G[...]]
  for (int idx = tid; idx < 64 * 128; idx += 256) {
    const int row = idx >> 7;
    const int ch = idx & 127;
    const int G = row >> 4, dl = row & 15;
    const int k = ch * 8;
    const float* src = (k < 512) ? Wp[G] + (d0 + dl) * E_ + k
                                 : Rp[G] + (d0 + dl) * H_ + (k - 512);
    short8 v;
#pragma unroll
    for (int s = 0; s < 8; ++s) v[s] = f2bs(src[s]);
    *(short8*)&wts[row * WROW + k] = v;
  }
  if (tid < 64) {
    const int G = tid >> 4, n = tid & 15;
    bias_s[G][n] = bp[G][d0 + n];
  }
  {
    const int m = tid >> 4, n = tid & 15;
    cbuf[m][n] = c0[(b0 + m) * H_ + d0 + n];
  }
  // h0 -> hbuf buffer 0, GROUP-LOCAL staging (each group stages its own 16
  // batches across its 32 blocks, so the seq flags cover the init stores).
  if (tid < 128) {
    const int u = g * 4096 + jb * 128 + tid;   // u32 index within slot 0
    unsigned pk = (unsigned)(unsigned short)f2bs(h0[2 * u]) |
                  ((unsigned)(unsigned short)f2bs(h0[2 * u + 1]) << 16);
    __hip_atomic_store(&hbuf32[u], pk, __ATOMIC_RELAXED,
                       __HIP_MEMORY_SCOPE_AGENT);
  }

  __syncthreads();  // wts/cbuf/bias visible; drains h0 stores (vmcnt(0))
  if (tid == 0)
    __hip_atomic_store(&seq_g[jb], 1u, __ATOMIC_RELAXED,
                       __HIP_MEMORY_SCOPE_AGENT);

  // per-wave pointers
  const short* xbase = (const short*)xe +
      (size_t)(b0 + l15) * T_ * E_ + w * 256 + q * 8;        // valid for w<2

  const int lds_base = l15 * WROW + w * 256 + q * 8;

  short8 cur[8];
  // prologue x-partials for t=0, then prefetch xe(1)
  if (w < 2) {
#pragma unroll
    for (int s = 0; s < 8; ++s) cur[s] = *(const short8*)(xbase + s * 32);
    floatx4 acc[4];
#pragma unroll
    for (int G = 0; G < 4; ++G) acc[G] = (floatx4){0.f, 0.f, 0.f, 0.f};
#pragma unroll
    for (int s = 0; s < 8; ++s)
#pragma unroll
      for (int G = 0; G < 4; ++G) {
        short8 bfr = *(const short8*)&wts[G * 16 * WROW + lds_base + s * 32];
        acc[G] = __builtin_amdgcn_mfma_f32_16x16x32_bf16(cur[s], bfr, acc[G], 0, 0, 0);
      }
#pragma unroll
    for (int G = 0; G < 4; ++G)
#pragma unroll
      for (int r = 0; r < 4; ++r)
        pbuf[w][G][q * 4 + r][l15] = acc[G][r];
#pragma unroll
    for (int s = 0; s < 8; ++s) cur[s] = *(const short8*)(xbase + E_ + s * 32);
  }

  for (int t = 0; t < T_; ++t) {
    if (w >= 2) {
      // ---- poll: all 32 blocks of the group published h(t) ----
      const unsigned tgt = (unsigned)(t + 1);
      for (;;) {
        unsigned v = __hip_atomic_load(&seq_g[lane & 31], __ATOMIC_RELAXED,
                                       __HIP_MEMORY_SCOPE_AGENT);
        if (__all((int)(v >= tgt))) break;
      }
      // ---- read h(t) rows via relaxed agent 8B atomic loads ----
      const ull_t* hb = hbuf64 + (size_t)(t & 1) * (B_ * H_ / 4) +
                        (b0 + l15) * (H_ / 4) + (w - 2) * 64 + q * 2;
      short8 hc[8];
#pragma unroll
      for (int s = 0; s < 8; ++s) {
        union { ull_t u[2]; short8 v8; } uu;
        uu.u[0] = __hip_atomic_load(hb + s * 8, __ATOMIC_RELAXED,
                                    __HIP_MEMORY_SCOPE_AGENT);
        uu.u[1] = __hip_atomic_load(hb + s * 8 + 1, __ATOMIC_RELAXED,
                                    __HIP_MEMORY_SCOPE_AGENT);
        hc[s] = uu.v8;
      }
      floatx4 acc[4];
#pragma unroll
      for (int G = 0; G < 4; ++G) acc[G] = (floatx4){0.f, 0.f, 0.f, 0.f};
#pragma unroll
      for (int s = 0; s < 8; ++s)
#pragma unroll
        for (int G = 0; G < 4; ++G) {
          short8 bfr = *(const short8*)&wts[G * 16 * WROW + lds_base + s * 32];
          acc[G] = __builtin_amdgcn_mfma_f32_16x16x32_bf16(hc[s], bfr, acc[G], 0, 0, 0);
        }
#pragma unroll
      for (int G = 0; G < 4; ++G)
#pragma unroll
        for (int r = 0; r < 4; ++r)
          pbuf[w][G][q * 4 + r][l15] = acc[G][r];
    }
    __syncthreads();  // sync1: pbuf (all 4 waves' partials) ready

    // ---- combine + activations: thread tid -> (m = tid>>4, n = tid&15) ----
    const int m = tid >> 4, n = tid & 15;
    float pre[4];
#pragma unroll
    for (int G = 0; G < 4; ++G)
      pre[G] = pbuf[0][G][m][n] + pbuf[1][G][m][n] + pbuf[2][G][m][n] +
               pbuf[3][G][m][n] + bias_s[G][n];
    const float iv = sigmoidf_(pre[0]);
    const float fv = sigmoidf_(pre[1]);
    const float gv = tanhf(pre[2]);
    const float ov = sigmoidf_(pre[3]);
    const float c = gv * iv + fv * cbuf[m][n];
    cbuf[m][n] = c;
    const float hval = ov * tanhf(c);

    // pack 2xbf16 with lane n^1 (same wave) and atomic-store (relaxed agent)
    {
      unsigned hv = (unsigned)(unsigned short)f2bs(hval);
      unsigned ov2 = __shfl_xor(hv, 1);
      if ((n & 1) == 0) {
        unsigned pk = hv | (ov2 << 16);
        __hip_atomic_store(
            &hbuf32[((t + 1) & 1) * (B_ * H_ / 2) + (b0 + m) * (H_ / 2) +
                    ((d0 + n) >> 1)],
            pk, __ATOMIC_RELAXED, __HIP_MEMORY_SCOPE_AGENT);
      }
    }
    __syncthreads();  // sync2: drains every wave's hbuf stores (vmcnt(0))
    if (tid == 0)
      __hip_atomic_store(&seq_g[jb], (unsigned)(t + 2), __ATOMIC_RELAXED,
                         __HIP_MEMORY_SCOPE_AGENT);

    // out store AFTER the flag publish: its HBM ack is off the critical path
    out[((size_t)(b0 + m) * T_ + t) * H_ + d0 + n] = hval;
    if (t == T_ - 1) {
      out[(size_t)B_ * T_ * H_ + (b0 + m) * H_ + d0 + n] = hval;
      out[(size_t)B_ * T_ * H_ + B_ * H_ + (b0 + m) * H_ + d0 + n] = c;
    }

    // waves 0,1: x-partials for step t+1 + xe prefetch, hidden under the
    // other waves' poll + h-load + h-MFMA of step t+1.
    if (w < 2 && t + 1 < T_) {
      floatx4 acc[4];
#pragma unroll
      for (int G = 0; G < 4; ++G) acc[G] = (floatx4){0.f, 0.f, 0.f, 0.f};
#pragma unroll
      for (int s = 0; s < 8; ++s)
#pragma unroll
        for (int G = 0; G < 4; ++G) {
          short8 bfr = *(const short8*)&wts[G * 16 * WROW + lds_base + s * 32];
          acc[G] = __builtin_amdgcn_mfma_f32_16x16x32_bf16(cur[s], bfr, acc[G], 0, 0, 0);
        }
#pragma unroll
      for (int G = 0; G < 4; ++G)
#pragma unroll
        for (int r = 0; r < 4; ++r)
          pbuf[w][G][q * 4 + r][l15] = acc[G][r];
      if (t + 2 < T_) {
        const short* xp = xbase + (size_t)(t + 2) * E_;
#pragma unroll
        for (int s = 0; s < 8; ++s) cur[s] = *(const short8*)(xp + s * 32);
      }
    }
  }
}

// ---------------------------------------------------------------------------
extern "C" void kernel_launch(void* const* d_in, const int* in_sizes, int n_in,
                              void* d_out, int out_size, void* d_ws,
                              size_t ws_size, hipStream_t stream) {
  const float* x_t = (const float*)d_in[0];
  const float* h0  = (const float*)d_in[1];
  const float* c0  = (const float*)d_in[2];
  const float* We  = (const float*)d_in[3];
  const float* be  = (const float*)d_in[4];
  const float* Wf  = (const float*)d_in[5];
  const float* bf_ = (const float*)d_in[6];
  const float* Wi  = (const float*)d_in[7];
  const float* bi  = (const float*)d_in[8];
  const float* Wg  = (const float*)d_in[9];
  const float* bg  = (const float*)d_in[10];
  const float* Wo  = (const float*)d_in[11];
  const float* bo  = (const float*)d_in[12];
  const float* Rf  = (const float*)d_in[13];
  const float* Ri  = (const float*)d_in[14];
  const float* Rg  = (const float*)d_in[15];
  const float* Ro  = (const float*)d_in[16];
  float* out = (float*)d_out;

  // workspace layout
  char* ws = (char*)d_ws;
  unsigned* seq  = (unsigned*)ws;                                 // 1024 B used
  unsigned* hbuf = (unsigned*)(ws + 4096);                        // 262144 B
  __hip_bfloat16* Web  = (__hip_bfloat16*)(ws + 4096 + 262144);   // 262144 B
  __hip_bfloat16* xe   = (__hip_bfloat16*)(ws + 4096 + 2 * 262144);

  hipMemsetAsync(seq, 0, 4096, stream);   // re-zero flags every launch

  cvt_we<<<(E_ * DIM_ + 255) / 256, 256, 0, stream>>>(We, Web, E_ * DIM_);

  embed_gemm<<<(B_ * T_) / 32, 256, 0, stream>>>(x_t, Web, be, xe);

  const size_t lds_bytes = 64 * WROW * sizeof(short);  // 132096
  lstm_persist<<<NG_ * NB_, 256, lds_bytes, stream>>>(
      h0, c0, Wi, bi, Wf, bf_, Wg, bg, Wo, bo, Ri, Rf, Rg, Ro, xe, hbuf, seq,
      out);
}

// Round 2
// 2038.802 us; speedup vs baseline: 1.1188x; 1.1188x over previous
//
#include <hip/hip_runtime.h>
#include <hip/hip_bf16.h>

#define B_ 128
#define T_ 512
#define DIM_ 256
#define E_ 512
#define H_ 512
#define NB_ 32        // blocks per batch-group (sync domain)
#define NG_ 8         // batch groups
#define WROW 1032     // padded LDS row stride (1024 + 8) in bf16 elems

typedef __attribute__((ext_vector_type(8))) short short8;
typedef __attribute__((ext_vector_type(4))) float floatx4;
typedef unsigned long long ull_t;

__device__ __forceinline__ float sigmoidf_(float x) {
  return __fdividef(1.0f, 1.0f + __expf(-x));
}

// fast tanh via __expf; clamp avoids inf/inf NaN. Error ~1e-6 abs, far below
// bf16 quantization of the h exchange.
__device__ __forceinline__ float tanhf_(float x) {
  x = fminf(15.0f, fmaxf(-15.0f, x));
  const float e = __expf(2.0f * x);
  return __fdividef(e - 1.0f, e + 1.0f);
}

__device__ __forceinline__ short f2bs(float f) {
  __hip_bfloat16 h = __float2bfloat16(f);
  return *reinterpret_cast<short*>(&h);
}

// ---------------------------------------------------------------------------
// Kernel 0: convert We (fp32) -> bf16 workspace copy.
// ---------------------------------------------------------------------------
__global__ __launch_bounds__(256) void cvt_we(const float* __restrict__ src,
                                              __hip_bfloat16* __restrict__ dst,
                                              int n) {
  int i = blockIdx.x * 256 + threadIdx.x;
  if (i < n) dst[i] = __float2bfloat16(src[i]);
}

// ---------------------------------------------------------------------------
// Kernel 1: xe[b*T+t][e] = sum_d x_t[b,t,d] * We[e,d] + be[e]   (bf16 out)
// ---------------------------------------------------------------------------
__global__ __launch_bounds__(256) void embed_gemm(
    const float* __restrict__ A,             // x_t  [65536][256] fp32
    const __hip_bfloat16* __restrict__ W,    // Web  [512][256] bf16
    const float* __restrict__ bias,          // be   [512] fp32
    __hip_bfloat16* __restrict__ C)          // xe   [65536][512] bf16
{
  const int tid = threadIdx.x;
  const int lane = tid & 63;
  const int w = tid >> 6;
  const int q = lane >> 4;
  const int l15 = lane & 15;
  const int m0 = blockIdx.x * 32 + (w >> 1) * 16;
  const int n0 = (w & 1) * 256;

  const float* a_base = A + (size_t)(m0 + l15) * DIM_ + q * 8;

  floatx4 acc[16];
#pragma unroll
  for (int j = 0; j < 16; ++j) acc[j] = (floatx4){0.f, 0.f, 0.f, 0.f};

  for (int ks = 0; ks < 8; ++ks) {
    const float* ap = a_base + ks * 32;
    short8 a;
#pragma unroll
    for (int j = 0; j < 8; ++j) a[j] = f2bs(ap[j]);
    short8 bf[16];
#pragma unroll
    for (int j = 0; j < 16; ++j) {
      const short* b_ptr =
          (const short*)W + (n0 + j * 16 + l15) * DIM_ + ks * 32 + q * 8;
      bf[j] = *(const short8*)b_ptr;
    }
#pragma unroll
    for (int j = 0; j < 16; ++j)
      acc[j] = __builtin_amdgcn_mfma_f32_16x16x32_bf16(a, bf[j], acc[j], 0, 0, 0);
  }

#pragma unroll
  for (int j = 0; j < 16; ++j) {
    const int col = n0 + j * 16 + l15;
    const float bv = bias[col];
#pragma unroll
    for (int r = 0; r < 4; ++r) {
      const int row = m0 + q * 4 + r;
      C[(size_t)row * E_ + col] = __float2bfloat16(acc[j][r] + bv);
    }
  }
}

// ---------------------------------------------------------------------------
// Kernel 2: persistent LSTM. 256 blocks (1/CU), 256 thr.
// block = (group g = blk&7, slice jb = blk>>3): batches [g*16,g*16+16),
// dims [jb*16, jb*16+16), all 4 gates. Weights [64 rows x 1024 K] in LDS.
//
// v3 schedule: all 4 waves split BOTH K-halves: wave w owns K-slice
// [w*128,(w+1)*128) of W (xe) AND of R (h).
//   - x-partials accX computed in the SHADOW (after publish, before wait)
//     into registers; merged for free as the h-MFMA C-in next step.
//   - critical path per step: wait -> h-load (4x16B/lane, agent atomics)
//     -> 16 MFMA -> pbuf -> sync -> combine (fast tanh) -> h-store ->
//     sync(drain) -> publish.
//   - shadow: out-store (HBM ack off path), 16 x-MFMA, xe prefetch.
// Sync = v1's proven protocol: per-group counter, relaxed agent fetch_add,
// tid0 spin with s_sleep backoff (NO multi-wave polling: v2 showed 64 waves
// hammering one line at the coherence point regresses 28%).
// ---------------------------------------------------------------------------
__global__ __launch_bounds__(256, 1) void lstm_persist(
    const float* __restrict__ h0,
    const float* __restrict__ c0,
    const float* __restrict__ Wi_, const float* __restrict__ bi_,
    const float* __restrict__ Wf_, const float* __restrict__ bf_,
    const float* __restrict__ Wg_, const float* __restrict__ bg_,
    const float* __restrict__ Wo_, const float* __restrict__ bo_,
    const float* __restrict__ Ri_, const float* __restrict__ Rf_,
    const float* __restrict__ Rg_, const float* __restrict__ Ro_,
    const __hip_bfloat16* __restrict__ xe,   // [B*T][E] bf16
    unsigned* __restrict__ hbuf32,           // [2][B][H/2] packed 2xbf16
    unsigned* __restrict__ cnt,              // group counters, stride 64 uints
    float* __restrict__ out)                 // hidden_seq | h_last | c_last
{
  extern __shared__ short wts[];             // 64 * WROW bf16 = 132096 B
  __shared__ float pbuf[4][4][16][17];       // [wave][gate][m][n] (+pad)
  __shared__ float cbuf[16][16];             // fp32 cell state slice
  __shared__ float bias_s[4][16];

  const int tid = threadIdx.x;
  const int lane = tid & 63;
  const int w = tid >> 6;
  const int q = lane >> 4;
  const int l15 = lane & 15;
  const int blk = blockIdx.x;
  const int g = blk & 7;        // batch group (XCD-local under %8 round-robin)
  const int jb = blk >> 3;      // dim slice
  const int b0 = g * 16;
  const int d0 = jb * 16;
  unsigned* cnt_g = cnt + g * 64;
  ull_t* hbuf64 = (ull_t*)hbuf32;

  const float* Wp[4] = {Wi_, Wf_, Wg_, Wo_};
  const float* Rp[4] = {Ri_, Rf_, Rg_, Ro_};
  const float* bp[4] = {bi_, bf_, bg_, bo_};

  // ---- load weights into LDS: row (G*16+dl) = [W_G[d0+dl][0:512] | R_G[...]]
  for (int idx = tid; idx < 64 * 128; idx += 256) {
    const int row = idx >> 7;
    const int ch = idx & 127;
    const int G = row >> 4, dl = row & 15;
    const int k = ch * 8;
    const float* src = (k < 512) ? Wp[G] + (d0 + dl) * E_ + k
                                 : Rp[G] + (d0 + dl) * H_ + (k - 512);
    short8 v;
#pragma unroll
    for (int s = 0; s < 8; ++s) v[s] = f2bs(src[s]);
    *(short8*)&wts[row * WROW + k] = v;
  }
  if (tid < 64) {
    const int G = tid >> 4, n = tid & 15;
    bias_s[G][n] = bp[G][d0 + n];
  }
  {
    const int m = tid >> 4, n = tid & 15;
    cbuf[m][n] = c0[(b0 + m) * H_ + d0 + n];
  }
  // h0 -> hbuf buffer 0, GROUP-LOCAL staging (the group's own counter
  // publication covers these stores).
  if (tid < 128) {
    const int u = g * 4096 + jb * 128 + tid;   // u32 index within slot 0
    unsigned pk = (unsigned)(unsigned short)f2bs(h0[2 * u]) |
                  ((unsigned)(unsigned short)f2bs(h0[2 * u + 1]) << 16);
    __hip_atomic_store(&hbuf32[u], pk, __ATOMIC_RELAXED,
                       __HIP_MEMORY_SCOPE_AGENT);
  }

  __syncthreads();  // wts/cbuf/bias visible; drains h0 stores (vmcnt(0))
  if (tid == 0)
    __hip_atomic_fetch_add(cnt_g, 1u, __ATOMIC_RELAXED,
                           __HIP_MEMORY_SCOPE_AGENT);

  // per-wave pointers: K-slice [w*128,(w+1)*128) of both halves
  const short* xbase = (const short*)xe +
      (size_t)(b0 + l15) * T_ * E_ + w * 128 + q * 8;
  const int lds_w = l15 * WROW + w * 128 + q * 8;    // W-part LDS base
  const int lds_r = lds_w + 512;                     // R-part LDS base

  short8 cur[4];
  floatx4 accX[4];

  // prologue: x-partials for t=0 (wts ready after the syncthreads above),
  // then prefetch xe(1)
#pragma unroll
  for (int s = 0; s < 4; ++s) cur[s] = *(const short8*)(xbase + s * 32);
#pragma unroll
  for (int G = 0; G < 4; ++G) accX[G] = (floatx4){0.f, 0.f, 0.f, 0.f};
#pragma unroll
  for (int s = 0; s < 4; ++s)
#pragma unroll
    for (int G = 0; G < 4; ++G) {
      short8 bfr = *(const short8*)&wts[G * 16 * WROW + lds_w + s * 32];
      accX[G] = __builtin_amdgcn_mfma_f32_16x16x32_bf16(cur[s], bfr, accX[G], 0, 0, 0);
    }
#pragma unroll
  for (int s = 0; s < 4; ++s) cur[s] = *(const short8*)(xbase + E_ + s * 32);

  for (int t = 0; t < T_; ++t) {
    // ---- wait: all 32 blocks of the group published h(t) ----
    if (tid == 0) {
      const unsigned tgt = (unsigned)(NB_ * (t + 1));
      while (__hip_atomic_load(cnt_g, __ATOMIC_RELAXED,
                               __HIP_MEMORY_SCOPE_AGENT) < tgt)
        __builtin_amdgcn_s_sleep(1);
    }
    __syncthreads();

    // ---- read h(t) rows via relaxed agent 8B atomic loads ----
    const ull_t* hb = hbuf64 + (size_t)(t & 1) * (B_ * H_ / 4) +
                      (b0 + l15) * (H_ / 4) + w * 32 + q * 2;
    short8 hc[4];
#pragma unroll
    for (int s = 0; s < 4; ++s) {
      union { ull_t u[2]; short8 v8; } uu;
      uu.u[0] = __hip_atomic_load(hb + s * 8, __ATOMIC_RELAXED,
                                  __HIP_MEMORY_SCOPE_AGENT);
      uu.u[1] = __hip_atomic_load(hb + s * 8 + 1, __ATOMIC_RELAXED,
                                  __HIP_MEMORY_SCOPE_AGENT);
      hc[s] = uu.v8;
    }

    // ---- h-MFMA with x-partials as C-in (free merge) ----
    floatx4 acc[4];
#pragma unroll
    for (int G = 0; G < 4; ++G) acc[G] = accX[G];
#pragma unroll
    for (int s = 0; s < 4; ++s)
#pragma unroll
      for (int G = 0; G < 4; ++G) {
        short8 bfr = *(const short8*)&wts[G * 16 * WROW + lds_r + s * 32];
        acc[G] = __builtin_amdgcn_mfma_f32_16x16x32_bf16(hc[s], bfr, acc[G], 0, 0, 0);
      }
#pragma unroll
    for (int G = 0; G < 4; ++G)
#pragma unroll
      for (int r = 0; r < 4; ++r)
        pbuf[w][G][q * 4 + r][l15] = acc[G][r];
    __syncthreads();  // sync1: all 4 waves' combined partials ready

    // ---- combine + activations: thread tid -> (m = tid>>4, n = tid&15) ----
    const int m = tid >> 4, n = tid & 15;
    float pre[4];
#pragma unroll
    for (int G = 0; G < 4; ++G)
      pre[G] = pbuf[0][G][m][n] + pbuf[1][G][m][n] + pbuf[2][G][m][n] +
               pbuf[3][G][m][n] + bias_s[G][n];
    const float iv = sigmoidf_(pre[0]);
    const float fv = sigmoidf_(pre[1]);
    const float gv = tanhf_(pre[2]);
    const float ov = sigmoidf_(pre[3]);
    const float cv = gv * iv + fv * cbuf[m][n];
    cbuf[m][n] = cv;
    const float hval = ov * tanhf_(cv);

    // pack 2xbf16 with lane n^1 (same wave) and atomic-store (relaxed agent)
    {
      unsigned hv = (unsigned)(unsigned short)f2bs(hval);
      unsigned ov2 = __shfl_xor(hv, 1);
      if ((n & 1) == 0) {
        unsigned pk = hv | (ov2 << 16);
        __hip_atomic_store(
            &hbuf32[((t + 1) & 1) * (B_ * H_ / 2) + (b0 + m) * (H_ / 2) +
                    ((d0 + n) >> 1)],
            pk, __ATOMIC_RELAXED, __HIP_MEMORY_SCOPE_AGENT);
      }
    }
    __syncthreads();  // sync2: every wave's vmcnt(0) -> h-stores at coherence pt
    if (tid == 0)
      __hip_atomic_fetch_add(cnt_g, 1u, __ATOMIC_RELAXED,
                             __HIP_MEMORY_SCOPE_AGENT);

    // ---- shadow (overlaps other blocks' skew + our next wait) ----
    out[((size_t)(b0 + m) * T_ + t) * H_ + d0 + n] = hval;
    if (t == T_ - 1) {
      out[(size_t)B_ * T_ * H_ + (b0 + m) * H_ + d0 + n] = hval;
      out[(size_t)B_ * T_ * H_ + B_ * H_ + (b0 + m) * H_ + d0 + n] = cv;
    }

    if (t + 1 < T_) {
      // x-partials for step t+1 from prefetched fragments
#pragma unroll
      for (int G = 0; G < 4; ++G) accX[G] = (floatx4){0.f, 0.f, 0.f, 0.f};
#pragma unroll
      for (int s = 0; s < 4; ++s)
#pragma unroll
        for (int G = 0; G < 4; ++G) {
          short8 bfr = *(const short8*)&wts[G * 16 * WROW + lds_w + s * 32];
          accX[G] = __builtin_amdgcn_mfma_f32_16x16x32_bf16(cur[s], bfr, accX[G], 0, 0, 0);
        }
      if (t + 2 < T_) {
        const short* xp = xbase + (size_t)(t + 2) * E_;
#pragma unroll
        for (int s = 0; s < 4; ++s) cur[s] = *(const short8*)(xp + s * 32);
      }
    }
  }
}

// ---------------------------------------------------------------------------
extern "C" void kernel_launch(void* const* d_in, const int* in_sizes, int n_in,
                              void* d_out, int out_size, void* d_ws,
                              size_t ws_size, hipStream_t stream) {
  const float* x_t = (const float*)d_in[0];
  const float* h0  = (const float*)d_in[1];
  const float* c0  = (const float*)d_in[2];
  const float* We  = (const float*)d_in[3];
  const float* be  = (const float*)d_in[4];
  const float* Wf  = (const float*)d_in[5];
  const float* bf_ = (const float*)d_in[6];
  const float* Wi  = (const float*)d_in[7];
  const float* bi  = (const float*)d_in[8];
  const float* Wg  = (const float*)d_in[9];
  const float* bg  = (const float*)d_in[10];
  const float* Wo  = (const float*)d_in[11];
  const float* bo  = (const float*)d_in[12];
  const float* Rf  = (const float*)d_in[13];
  const float* Ri  = (const float*)d_in[14];
  const float* Rg  = (const float*)d_in[15];
  const float* Ro  = (const float*)d_in[16];
  float* out = (float*)d_out;

  // workspace layout
  char* ws = (char*)d_ws;
  unsigned* cnt  = (unsigned*)ws;                                 // 2048 B
  unsigned* hbuf = (unsigned*)(ws + 4096);                        // 262144 B
  __hip_bfloat16* Web  = (__hip_bfloat16*)(ws + 4096 + 262144);   // 262144 B
  __hip_bfloat16* xe   = (__hip_bfloat16*)(ws + 4096 + 2 * 262144);

  hipMemsetAsync(cnt, 0, 2048, stream);

  cvt_we<<<(E_ * DIM_ + 255) / 256, 256, 0, stream>>>(We, Web, E_ * DIM_);

  embed_gemm<<<(B_ * T_) / 32, 256, 0, stream>>>(x_t, Web, be, xe);

  const size_t lds_bytes = 64 * WROW * sizeof(short);  // 132096
  lstm_persist<<<NG_ * NB_, 256, lds_bytes, stream>>>(
      h0, c0, Wi, bi, Wf, bf_, Wg, bg, Wo, bo, Ri, Rf, Rg, Ro, xe, hbuf, cnt,
      out);
}

// Round 3
// 2034.768 us; speedup vs baseline: 1.1211x; 1.0020x over previous
//
#include <hip/hip_runtime.h>
#include <hip/hip_bf16.h>

#define B_ 128
#define T_ 512
#define DIM_ 256
#define E_ 512
#define H_ 512
#define NB_ 32        // blocks per batch-group (sync domain)
#define NG_ 8         // batch groups
#define WROW 1032     // padded LDS row stride (1024 + 8) in bf16 elems
#define FSTRIDE 32    // u32 stride between seq flags: 128 B = own cacheline

typedef __attribute__((ext_vector_type(8))) short short8;
typedef __attribute__((ext_vector_type(4))) float floatx4;
typedef unsigned long long ull_t;

__device__ __forceinline__ float sigmoidf_(float x) {
  return __fdividef(1.0f, 1.0f + __expf(-x));
}

// fast tanh via __expf; clamp avoids inf/inf NaN. Error ~1e-6 abs, far below
// the bf16 quantization of the h exchange.
__device__ __forceinline__ float tanhf_(float x) {
  x = fminf(15.0f, fmaxf(-15.0f, x));
  const float e = __expf(2.0f * x);
  return __fdividef(e - 1.0f, e + 1.0f);
}

__device__ __forceinline__ short f2bs(float f) {
  __hip_bfloat16 h = __float2bfloat16(f);
  return *reinterpret_cast<short*>(&h);
}

// ---------------------------------------------------------------------------
// Kernel 0: convert We (fp32) -> bf16 workspace copy.
// ---------------------------------------------------------------------------
__global__ __launch_bounds__(256) void cvt_we(const float* __restrict__ src,
                                              __hip_bfloat16* __restrict__ dst,
                                              int n) {
  int i = blockIdx.x * 256 + threadIdx.x;
  if (i < n) dst[i] = __float2bfloat16(src[i]);
}

// ---------------------------------------------------------------------------
// Kernel 1: xe[b*T+t][e] = sum_d x_t[b,t,d] * We[e,d] + be[e]   (bf16 out)
// ---------------------------------------------------------------------------
__global__ __launch_bounds__(256) void embed_gemm(
    const float* __restrict__ A,             // x_t  [65536][256] fp32
    const __hip_bfloat16* __restrict__ W,    // Web  [512][256] bf16
    const float* __restrict__ bias,          // be   [512] fp32
    __hip_bfloat16* __restrict__ C)          // xe   [65536][512] bf16
{
  const int tid = threadIdx.x;
  const int lane = tid & 63;
  const int w = tid >> 6;
  const int q = lane >> 4;
  const int l15 = lane & 15;
  const int m0 = blockIdx.x * 32 + (w >> 1) * 16;
  const int n0 = (w & 1) * 256;

  const float* a_base = A + (size_t)(m0 + l15) * DIM_ + q * 8;

  floatx4 acc[16];
#pragma unroll
  for (int j = 0; j < 16; ++j) acc[j] = (floatx4){0.f, 0.f, 0.f, 0.f};

  for (int ks = 0; ks < 8; ++ks) {
    const float* ap = a_base + ks * 32;
    short8 a;
#pragma unroll
    for (int j = 0; j < 8; ++j) a[j] = f2bs(ap[j]);
    short8 bf[16];
#pragma unroll
    for (int j = 0; j < 16; ++j) {
      const short* b_ptr =
          (const short*)W + (n0 + j * 16 + l15) * DIM_ + ks * 32 + q * 8;
      bf[j] = *(const short8*)b_ptr;
    }
#pragma unroll
    for (int j = 0; j < 16; ++j)
      acc[j] = __builtin_amdgcn_mfma_f32_16x16x32_bf16(a, bf[j], acc[j], 0, 0, 0);
  }

#pragma unroll
  for (int j = 0; j < 16; ++j) {
    const int col = n0 + j * 16 + l15;
    const float bv = bias[col];
#pragma unroll
    for (int r = 0; r < 4; ++r) {
      const int row = m0 + q * 4 + r;
      C[(size_t)row * E_ + col] = __float2bfloat16(acc[j][r] + bv);
    }
  }
}

// ---------------------------------------------------------------------------
// Kernel 2: persistent LSTM. 256 blocks (1/CU), 256 thr.
// block = (group g = blk&7, slice jb = blk>>3): batches [g*16,g*16+16),
// dims [jb*16, jb*16+16), all 4 gates. Weights [64 rows x 1024 K] in LDS.
// Wave w: K-range [w*256,(w+1)*256): waves 0,1 -> xe (W), 2,3 -> h (R).
// (v1's proven parallel-wave split; v3's serialize-into-shadow regressed.)
//
// SYNC v4 — per-block flags, single gather-poller:
//   flags_g[jb*FSTRIDE] = t+2 ("my h(t+1) slice is at the coherence point").
//   Publish: ONE relaxed agent store to the block's OWN cacheline after the
//   post-h-store __syncthreads (its vmcnt(0) drain makes all 4 waves' hbuf
//   stores globally visible first). No RMW -> no 32-deep same-line atomic
//   serialization (v1), no s_sleep wake quantization.
//   Wait: wave 3 ONLY (v2 showed 64 pollers on one line regress 28%) gathers
//   the 32 flag lines (2 lanes/line) + __all ballot; one L2 RTT per iter.
//   Wave 3 is an h-wave: no outstanding VMEM at poll time, so the implicit
//   vmcnt wait before reading flag values costs nothing (wave 0 would stall
//   on its xe-prefetch acks).
//   out-store: issued at the TOP of the next step (all waves), so its ack
//   drains at that step's pbuf barrier ~600+ cyc later -> off the publish
//   and poll paths.
// ---------------------------------------------------------------------------
__global__ __launch_bounds__(256, 1) void lstm_persist(
    const float* __restrict__ h0,
    const float* __restrict__ c0,
    const float* __restrict__ Wi_, const float* __restrict__ bi_,
    const float* __restrict__ Wf_, const float* __restrict__ bf_,
    const float* __restrict__ Wg_, const float* __restrict__ bg_,
    const float* __restrict__ Wo_, const float* __restrict__ bo_,
    const float* __restrict__ Ri_, const float* __restrict__ Rf_,
    const float* __restrict__ Rg_, const float* __restrict__ Ro_,
    const __hip_bfloat16* __restrict__ xe,   // [B*T][E] bf16
    unsigned* __restrict__ hbuf32,           // [2][B][H/2] packed 2xbf16
    unsigned* __restrict__ flags,            // [NG_][NB_] seq flags, 128B apart
    float* __restrict__ out)                 // hidden_seq | h_last | c_last
{
  extern __shared__ short wts[];             // 64 * WROW bf16 = 132096 B
  __shared__ float pbuf[4][4][16][17];       // [wave][gate][m][n] (+pad)
  __shared__ float cbuf[16][16];             // fp32 cell state slice
  __shared__ float bias_s[4][16];

  const int tid = threadIdx.x;
  const int lane = tid & 63;
  const int w = tid >> 6;
  const int q = lane >> 4;
  const int l15 = lane & 15;
  const int blk = blockIdx.x;
  const int g = blk & 7;        // batch group (XCD-local under %8 round-robin)
  const int jb = blk >> 3;      // dim slice
  const int b0 = g * 16;
  const int d0 = jb * 16;
  unsigned* flags_g = flags + g * (NB_ * FSTRIDE);
  ull_t* hbuf64 = (ull_t*)hbuf32;

  const float* Wp[4] = {Wi_, Wf_, Wg_, Wo_};
  const float* Rp[4] = {Ri_, Rf_, Rg_, Ro_};
  const float* bp[4] = {bi_, bf_, bg_, bo_};

  // ---- load weights into LDS: row (G*16+dl) = [W_G[d0+dl][0:512] | R_G[...]]
  for (int idx = tid; idx < 64 * 128; idx += 256) {
    const int row = idx >> 7;
    const int ch = idx & 127;
    const int G = row >> 4, dl = row & 15;
    const int k = ch * 8;
    const float* src = (k < 512) ? Wp[G] + (d0 + dl) * E_ + k
                                 : Rp[G] + (d0 + dl) * H_ + (k - 512);
    short8 v;
#pragma unroll
    for (int s = 0; s < 8; ++s) v[s] = f2bs(src[s]);
    *(short8*)&wts[row * WROW + k] = v;
  }
  if (tid < 64) {
    const int G = tid >> 4, n = tid & 15;
    bias_s[G][n] = bp[G][d0 + n];
  }
  {
    const int m = tid >> 4, n = tid & 15;
    cbuf[m][n] = c0[(b0 + m) * H_ + d0 + n];
  }
  // h0 -> hbuf buffer 0, GROUP-LOCAL staging (the group's own flags cover
  // these stores).
  if (tid < 128) {
    const int u = g * 4096 + jb * 128 + tid;   // u32 index within slot 0
    unsigned pk = (unsigned)(unsigned short)f2bs(h0[2 * u]) |
                  ((unsigned)(unsigned short)f2bs(h0[2 * u + 1]) << 16);
    __hip_atomic_store(&hbuf32[u], pk, __ATOMIC_RELAXED,
                       __HIP_MEMORY_SCOPE_AGENT);
  }

  __syncthreads();  // wts/cbuf/bias visible; drains h0 stores (vmcnt(0))
  if (tid == 0)
    __hip_atomic_store(&flags_g[jb * FSTRIDE], 1u, __ATOMIC_RELAXED,
                       __HIP_MEMORY_SCOPE_AGENT);

  // per-wave pointers
  const short* xbase = (const short*)xe +
      (size_t)(b0 + l15) * T_ * E_ + w * 256 + q * 8;        // valid for w<2
  const int lds_base = l15 * WROW + w * 256 + q * 8;

  short8 cur[8];
  if (w < 2) {
#pragma unroll
    for (int s = 0; s < 8; ++s) cur[s] = *(const short8*)(xbase + s * 32);
  }

  // pre-loop wait: all 32 blocks of the group staged h(0)
  if (w == 3) {
    unsigned* fp = &flags_g[(lane & 31) * FSTRIDE];
    for (;;) {
      unsigned v = __hip_atomic_load(fp, __ATOMIC_RELAXED,
                                     __HIP_MEMORY_SCOPE_AGENT);
      if (__all((int)(v >= 1u))) break;
    }
  }
  __syncthreads();

  float hval = 0.f, cv = 0.f;
  const int m = tid >> 4, n = tid & 15;

  for (int t = 0; t < T_; ++t) {
    // out-store of the PREVIOUS step: issues under this step's h-load /
    // x-MFMA, ack drains at the pbuf barrier far downstream.
    if (t > 0)
      out[((size_t)(b0 + m) * T_ + (t - 1)) * H_ + d0 + n] = hval;

    if (w >= 2) {
      // ---- read h(t) rows via relaxed agent 8B atomic loads ----
      const ull_t* hb = hbuf64 + (size_t)(t & 1) * (B_ * H_ / 4) +
                        (b0 + l15) * (H_ / 4) + (w - 2) * 64 + q * 2;
#pragma unroll
      for (int s = 0; s < 8; ++s) {
        union { ull_t u[2]; short8 v8; } uu;
        uu.u[0] = __hip_atomic_load(hb + s * 8, __ATOMIC_RELAXED,
                                    __HIP_MEMORY_SCOPE_AGENT);
        uu.u[1] = __hip_atomic_load(hb + s * 8 + 1, __ATOMIC_RELAXED,
                                    __HIP_MEMORY_SCOPE_AGENT);
        cur[s] = uu.v8;
      }
    }

    floatx4 acc[4];
#pragma unroll
    for (int G = 0; G < 4; ++G) acc[G] = (floatx4){0.f, 0.f, 0.f, 0.f};
#pragma unroll
    for (int s = 0; s < 8; ++s)
#pragma unroll
      for (int G = 0; G < 4; ++G) {
        short8 bfr = *(const short8*)&wts[G * 16 * WROW + lds_base + s * 32];
        acc[G] = __builtin_amdgcn_mfma_f32_16x16x32_bf16(cur[s], bfr, acc[G], 0, 0, 0);
      }

    // prefetch next step's xe fragments (read-only: safe across barriers)
    if (w < 2 && t + 1 < T_) {
      const short* xp = xbase + (size_t)(t + 1) * E_;
#pragma unroll
      for (int s = 0; s < 8; ++s) cur[s] = *(const short8*)(xp + s * 32);
    }

#pragma unroll
    for (int G = 0; G < 4; ++G)
#pragma unroll
      for (int r = 0; r < 4; ++r)
        pbuf[w][G][q * 4 + r][l15] = acc[G][r];
    __syncthreads();  // sync1: all 4 waves' partials ready

    // ---- combine + activations ----
    float pre[4];
#pragma unroll
    for (int G = 0; G < 4; ++G)
      pre[G] = pbuf[0][G][m][n] + pbuf[1][G][m][n] + pbuf[2][G][m][n] +
               pbuf[3][G][m][n] + bias_s[G][n];
    const float iv = sigmoidf_(pre[0]);
    const float fv = sigmoidf_(pre[1]);
    const float gv = tanhf_(pre[2]);
    const float ov = sigmoidf_(pre[3]);
    cv = gv * iv + fv * cbuf[m][n];
    cbuf[m][n] = cv;
    hval = ov * tanhf_(cv);

    if (t + 1 < T_) {
      // pack 2xbf16 with lane n^1 and atomic-store (relaxed agent)
      unsigned hv = (unsigned)(unsigned short)f2bs(hval);
      unsigned ov2 = __shfl_xor(hv, 1);
      if ((n & 1) == 0) {
        unsigned pk = hv | (ov2 << 16);
        __hip_atomic_store(
            &hbuf32[((t + 1) & 1) * (B_ * H_ / 2) + (b0 + m) * (H_ / 2) +
                    ((d0 + n) >> 1)],
            pk, __ATOMIC_RELAXED, __HIP_MEMORY_SCOPE_AGENT);
      }
      __syncthreads();  // sync2: every wave's vmcnt(0) -> h-stores visible
      if (tid == 0)
        __hip_atomic_store(&flags_g[jb * FSTRIDE], (unsigned)(t + 2),
                           __ATOMIC_RELAXED, __HIP_MEMORY_SCOPE_AGENT);
      // ---- wait: all 32 blocks published h(t+1); wave 3 gathers 32 lines
      if (w == 3) {
        unsigned* fp = &flags_g[(lane & 31) * FSTRIDE];
        const unsigned tgt = (unsigned)(t + 2);
        for (;;) {
          unsigned v = __hip_atomic_load(fp, __ATOMIC_RELAXED,
                                         __HIP_MEMORY_SCOPE_AGENT);
          if (__all((int)(v >= tgt))) break;
        }
      }
      __syncthreads();  // sync3: wake; h(t+1) readable by all waves
    }
  }

  // epilogue: last-step outputs
  out[((size_t)(b0 + m) * T_ + (T_ - 1)) * H_ + d0 + n] = hval;
  out[(size_t)B_ * T_ * H_ + (b0 + m) * H_ + d0 + n] = hval;
  out[(size_t)B_ * T_ * H_ + B_ * H_ + (b0 + m) * H_ + d0 + n] = cv;
}

// ---------------------------------------------------------------------------
extern "C" void kernel_launch(void* const* d_in, const int* in_sizes, int n_in,
                              void* d_out, int out_size, void* d_ws,
                              size_t ws_size, hipStream_t stream) {
  const float* x_t = (const float*)d_in[0];
  const float* h0  = (const float*)d_in[1];
  const float* c0  = (const float*)d_in[2];
  const float* We  = (const float*)d_in[3];
  const float* be  = (const float*)d_in[4];
  const float* Wf  = (const float*)d_in[5];
  const float* bf_ = (const float*)d_in[6];
  const float* Wi  = (const float*)d_in[7];
  const float* bi  = (const float*)d_in[8];
  const float* Wg  = (const float*)d_in[9];
  const float* bg  = (const float*)d_in[10];
  const float* Wo  = (const float*)d_in[11];
  const float* bo  = (const float*)d_in[12];
  const float* Rf  = (const float*)d_in[13];
  const float* Ri  = (const float*)d_in[14];
  const float* Rg  = (const float*)d_in[15];
  const float* Ro  = (const float*)d_in[16];
  float* out = (float*)d_out;

  // workspace layout
  char* ws = (char*)d_ws;
  unsigned* flags = (unsigned*)ws;                                 // 32768 B
  unsigned* hbuf  = (unsigned*)(ws + 32768);                       // 262144 B
  __hip_bfloat16* Web = (__hip_bfloat16*)(ws + 32768 + 262144);    // 262144 B
  __hip_bfloat16* xe  = (__hip_bfloat16*)(ws + 32768 + 2 * 262144);

  hipMemsetAsync(flags, 0, 32768, stream);

  cvt_we<<<(E_ * DIM_ + 255) / 256, 256, 0, stream>>>(We, Web, E_ * DIM_);

  embed_gemm<<<(B_ * T_) / 32, 256, 0, stream>>>(x_t, Web, be, xe);

  const size_t lds_bytes = 64 * WROW * sizeof(short);  // 132096
  lstm_persist<<<NG_ * NB_, 256, lds_bytes, stream>>>(
      h0, c0, Wi, bi, Wf, bf_, Wg, bg, Wo, bo, Ri, Rf, Rg, Ro, xe, hbuf, flags,
      out);
}